// Round 3
// baseline (216.252 us; speedup 1.0000x reference)
//
#include <hip/hip_runtime.h>
#include <stdint.h>

#define F_IN 65536
#define NN 100
#define CO 60
#define G_SPLIT 128
#define KC (F_IN/G_SPLIT)   // 512
#define BK 64
#define NIT (KC/BK)         // 8

typedef short v8s __attribute__((ext_vector_type(8)));
typedef float v4f __attribute__((ext_vector_type(4)));

__device__ __forceinline__ unsigned int f2bf(float x){
  unsigned int u = __float_as_uint(x);
  u += 0x7fffu + ((u>>16)&1u);      // round-to-nearest-even
  return u>>16;
}
__device__ __forceinline__ v4f mfma16(v8s a, v8s b, v4f c){
  return __builtin_amdgcn_mfma_f32_16x16x32_bf16(a,b,c,0,0,0);
}
// async global->LDS, 16 B per lane, zero VGPR round-trip, tracked by vmcnt.
// HW semantics: LDS dest = wave-uniform base + lane*16 (we pass exactly that).
__device__ __forceinline__ void cp16(const void* g, void* l){
  __builtin_amdgcn_global_load_lds((const __attribute__((address_space(1))) void*)g,
                                   (__attribute__((address_space(3))) void*)l, 16, 0, 0);
}

// ---------------------------------------------------------------------------
// K0: x (f32) -> xb (bf16), once.  26 MB read / 13 MB write, HBM-bound.
// ---------------------------------------------------------------------------
__global__ __launch_bounds__(256)
void k_cvt(const float* __restrict__ x, unsigned short* __restrict__ xb){
  int i = blockIdx.x*256 + threadIdx.x;           // 6400*256*4 == 6,553,600 exactly
  float4 v = ((const float4*)x)[i];
  uint2 w;
  w.x = f2bf(v.x) | (f2bf(v.y)<<16);
  w.y = f2bf(v.z) | (f2bf(v.w)<<16);
  ((uint2*)xb)[i] = w;
}

// ---------------------------------------------------------------------------
// K1: split-K GEMM.  grid=(G_SPLIT,6).  All staging is async global_load_lds
// (no VGPR loads for the compiler to serialize).  Double-buffered LDS, one
// barrier per K-iter; DMA for it+1 issued right after the barrier so it
// flies behind the MFMA phase of it (m97 structure).
//
// A (bf16 x): 112x64 tile, row stride 64 shorts (128 B).  16B chunks XOR-
// swizzled by (row&7) on the GLOBAL gather side (async DMA lands lanes
// contiguously, so LDS physical layout can't be padded) -> frag b128 reads
// hit 8 distinct bank groups (2-way alias = free).
// W (f32): each BK-slab is 15360 contiguous bytes -> straight 1KB/lane-group
// copy; B-frags built with per-element cvt from LDS.
// ---------------------------------------------------------------------------
__global__ __launch_bounds__(256,2)
void k_gemm(const unsigned short* __restrict__ xb, const float* __restrict__ aw,
            const float* __restrict__ cw, float* __restrict__ dst, int partial){
  const int s = blockIdx.x, g = blockIdx.y;
  const int k0 = s*KC;
  const int tid = threadIdx.x, wave = tid>>6, lane = tid&63, quad = lane>>4, nl = lane&15;
  const int c0 = wave*16, ccl = min(c0+nl, CO-1);   // clamp pad cols; discarded at store

  __shared__ __align__(16) unsigned short Ab[2][112*64];   // 28,672 B
  __shared__ __align__(16) float          Wb[2][BK*CO];    // 30,720 B

  const float* W = (g<3) ? (aw + (size_t)g*F_IN*CO) : (cw + (size_t)(g-3)*F_IN*CO);

  // --- per-lane DMA source pointers & LDS offsets (computed once) ---
  const int nA = (wave<2) ? 4 : 3;      // 14 A-instructions over 4 waves
  const int nW = (wave<3) ? 4 : 3;      // 15 W-instructions over 4 waves
  const unsigned short* ag[4];
  unsigned int aoff[4];
  #pragma unroll
  for(int ti=0; ti<4; ++ti){
    int t   = wave + 4*ti;              // instruction id 0..13
    int row = 8*t + (lane>>3);          // physical LDS row 0..111
    int rcl = min(row, NN-1);           // rows >=100 clone row 99 (outputs discarded)
    int lch = (lane&7) ^ (row&7);       // logical 16B chunk for this physical slot
    ag[ti]  = xb + (size_t)rcl*F_IN + k0 + lch*8;
    aoff[ti] = t*512 + lane*8;          // shorts; == base(t*1KB) + lane*16B
  }
  const float* wg[4];
  unsigned int woff[4];
  #pragma unroll
  for(int ti=0; ti<4; ++ti){
    int t = wave + 4*ti;                // instruction id 0..14
    wg[ti]   = W + (size_t)k0*CO + t*256 + lane*4;
    woff[ti] = t*256 + lane*4;          // floats; == base(t*1KB) + lane*16B
  }

  v4f acc[7];
  #pragma unroll
  for(int i=0;i<7;++i){ v4f z={0.f,0.f,0.f,0.f}; acc[i]=z; }

  // --- prefetch iter 0 into buffer 0 ---
  #pragma unroll
  for(int ti=0; ti<4; ++ti) if(ti<nA) cp16(ag[ti], &Ab[0][aoff[ti]]);
  #pragma unroll
  for(int ti=0; ti<4; ++ti) if(ti<nW) cp16(wg[ti], &Wb[0][woff[ti]]);

  for(int it=0; it<NIT; ++it){
    __syncthreads();                    // drains vmcnt -> buf[it&1] ready; guards buf reuse
    const int b = it&1;
    if(it+1 < NIT){
      const int nb = (it+1)&1;
      #pragma unroll
      for(int ti=0; ti<4; ++ti) if(ti<nA) cp16(ag[ti] + (it+1)*BK, &Ab[nb][aoff[ti]]);
      #pragma unroll
      for(int ti=0; ti<4; ++ti) if(ti<nW) cp16(wg[ti] + (size_t)(it+1)*BK*CO, &Wb[nb][woff[ti]]);
    }
    // --- B fragments: strided f32 LDS reads + cvt ---
    v8s fB0, fB1;
    #pragma unroll
    for(int j=0;j<8;++j){
      fB0[j] = (short)f2bf(Wb[b][(   quad*8+j)*CO + ccl]);
      fB1[j] = (short)f2bf(Wb[b][(32+quad*8+j)*CO + ccl]);
    }
    // --- MFMA over 7 m-tiles (M padded 100->112) ---
    #pragma unroll
    for(int mt=0; mt<7; ++mt){
      int r  = mt*16 + nl;
      int p0 = ((quad ^ (r&7))*8);      // de-swizzle: phys chunk of logical chunk `quad`
      v8s a0 = *(const v8s*)&Ab[b][r*64 + p0];          // k = quad*8+j
      v8s a1 = *(const v8s*)&Ab[b][r*64 + (p0^32)];     // k = 32+quad*8+j
      acc[mt] = mfma16(a0, fB0, acc[mt]);
      acc[mt] = mfma16(a1, fB1, acc[mt]);
    }
  }

  // --- epilogue.  C/D layout: col=lane&15, row=quad*4+i ---
  const int c = c0 + nl;
  if(c < CO){
    if(partial){
      float* pd = dst + ((size_t)g*G_SPLIT + s)*(NN*CO);
      #pragma unroll
      for(int mt=0;mt<7;++mt){
        #pragma unroll
        for(int i=0;i<4;++i){
          int m = mt*16 + quad*4 + i;
          if(m < NN) pd[m*CO + c] = acc[mt][i];
        }
      }
    } else {
      float* pd = dst + (size_t)g*(NN*CO);
      #pragma unroll
      for(int mt=0;mt<7;++mt){
        #pragma unroll
        for(int i=0;i<4;++i){
          int m = mt*16 + quad*4 + i;
          if(m < NN) atomicAdd(pd + m*CO + c, acc[mt][i]);
        }
      }
    }
  }
}

// ---------------------------------------------------------------------------
// K1b: split-K reduce.  grid=(141,4); block (b,q) sums 32 slices of P into Y
// via atomicAdd (Y zeroed by memset).  Reads coalesced (stride 6000 floats).
// ---------------------------------------------------------------------------
__global__ void k_reduce(const float* __restrict__ P, float* __restrict__ Y){
  int o = blockIdx.x*256 + threadIdx.x;
  if(o >= 6*NN*CO) return;
  int gg = o/(NN*CO), r = o - gg*(NN*CO);
  const float* p = P + (size_t)gg*G_SPLIT*(NN*CO) + (size_t)blockIdx.y*32*(NN*CO) + r;
  float a0=0.f,a1=0.f,a2=0.f,a3=0.f;
  #pragma unroll 2
  for(int s4=0;s4<32;s4+=4){
    a0 += p[(s4  )*(NN*CO)];
    a1 += p[(s4+1)*(NN*CO)];
    a2 += p[(s4+2)*(NN*CO)];
    a3 += p[(s4+3)*(NN*CO)];
  }
  atomicAdd(&Y[o], (a0+a1)+(a2+a3));
}

// ---------------------------------------------------------------------------
// K2: cheb combine.  out = Y0 - Y2 + L@(Y1 + 2*L@Y2) + b, then tanh.
// One block per (net, output column c).  L (100x100) rebuilt in LDS per block.
// ---------------------------------------------------------------------------
__global__ void k_cheb(const float* __restrict__ Y, const int* __restrict__ ei,
                       const float* __restrict__ ab, const float* __restrict__ cb,
                       float* __restrict__ emb){
  const int net = blockIdx.x / CO;
  const int c   = blockIdx.x % CO;
  const int t   = threadIdx.x;       // 128
  __shared__ float L[NN][NN+1];      // stride 101: 2-way bank alias only
  __shared__ float dis[NN];
  __shared__ int   deg[NN];
  __shared__ float y0[NN], y1[NN], y2[NN], zu[NN];

  for(int i=t;i<NN*(NN+1);i+=128) ((float*)L)[i]=0.f;
  if(t<NN) deg[t]=0;
  __syncthreads();
  for(int e=t;e<2000;e+=128) atomicAdd(&deg[ei[e]],1);
  __syncthreads();
  if(t<NN) dis[t] = deg[t]>0 ? rsqrtf((float)deg[t]) : 0.f;
  __syncthreads();
  for(int e=t;e<2000;e+=128){
    int s = ei[e], d = ei[2000+e];
    atomicAdd(&L[d][s], -dis[s]*dis[d]);
  }
  if(t<NN){
    const float* yb = Y + (size_t)net*3*NN*CO + t*CO + c;
    y0[t]=yb[0]; y1[t]=yb[NN*CO]; y2[t]=yb[2*NN*CO];
  }
  __syncthreads();
  if(t<NN){
    float s=0.f;
    #pragma unroll 4
    for(int j=0;j<NN;++j) s += L[t][j]*y2[j];
    zu[t] = y1[t] + 2.f*s;
  }
  __syncthreads();
  if(t<NN){
    float s=0.f;
    #pragma unroll 4
    for(int j=0;j<NN;++j) s += L[t][j]*zu[j];
    float b = (net==0) ? ab[c] : cb[c];
    emb[net*NN*CO + t*CO + c] = tanhf(y0[t] - y2[t] + s + b);
  }
}

// ---------------------------------------------------------------------------
// K3: final FC.  out zeroed by memset.  Blocks 0..24: coalesced logits
// partials (lane = output column j, 240 i-rows per block), atomicAdd.
// Block 25: value dot + biases + scalar extras.
// ---------------------------------------------------------------------------
#define FCB 25
__global__ void k_fc(const float* __restrict__ emb, const float* __restrict__ afw,
                     const float* __restrict__ afb, const float* __restrict__ cfw,
                     const float* __restrict__ cfb, const float* __restrict__ s0,
                     const float* __restrict__ s1, const float* __restrict__ s2,
                     float* __restrict__ out){
  const int b = blockIdx.x;
  const int t = threadIdx.x;         // 256
  if(b < FCB){
    const int jj = t & 127, half = t >> 7;
    if(jj < 100){
      const int i0 = b*240 + half*120;
      const float* w = afw + (size_t)i0*100 + jj;
      const float* e = emb + i0;
      float p = 0.f;
      #pragma unroll 4
      for(int i=0;i<120;++i) p += e[i]*w[(size_t)i*100];
      atomicAdd(&out[jj], p);
    }
  } else {
    float p = 0.f;
    const float* e = emb + 6000;
    for(int i=t;i<6000;i+=256) p += e[i]*cfw[i];
    #pragma unroll
    for(int o=32;o>0;o>>=1) p += __shfl_down(p,o,64);
    __shared__ float red[4];
    if((t&63)==0) red[t>>6]=p;
    __syncthreads();
    if(t==0){
      float tot = red[0]+red[1]+red[2]+red[3];
      out[100] = tot + s0[0]*cfw[6000] + s1[0]*cfw[6001] + s2[0]*cfw[6002] + cfb[0];
    }
    if(t<100){
      atomicAdd(&out[t], afb[t] + s0[0]*afw[600000+t] + s1[0]*afw[600100+t] + s2[0]*afw[600200+t]);
    }
  }
}

extern "C" void kernel_launch(void* const* d_in, const int* in_sizes, int n_in,
                              void* d_out, int out_size, void* d_ws, size_t ws_size,
                              hipStream_t stream){
  const float* x   = (const float*)d_in[0];
  const int*   ei  = (const int*)d_in[1];
  const float* s0  = (const float*)d_in[2];
  const float* s1  = (const float*)d_in[3];
  const float* s2  = (const float*)d_in[4];
  const float* aw  = (const float*)d_in[5];
  const float* ab  = (const float*)d_in[6];
  const float* cw  = (const float*)d_in[7];
  const float* cb  = (const float*)d_in[8];
  const float* afw = (const float*)d_in[9];
  const float* afb = (const float*)d_in[10];
  const float* cfw = (const float*)d_in[11];
  const float* cfb = (const float*)d_in[12];
  float* out = (float*)d_out;

  // ws layout: xb (13,107,200 B) | Y (144,000 B) | emb (48,000 B) | P (18,432,000 B)
  unsigned short* xb = (unsigned short*)d_ws;
  float* Y   = (float*)((char*)d_ws + 13107200);
  float* emb = Y + 6*NN*CO;
  float* P   = emb + 2*NN*CO;
  const size_t need_full = 13107200u + (size_t)(6*NN*CO + 2*NN*CO)*4 + (size_t)6*G_SPLIT*NN*CO*4;
  const int partial = (ws_size >= need_full) ? 1 : 0;

  hipMemsetAsync(Y, 0, 6*NN*CO*sizeof(float), stream);
  hipMemsetAsync(out, 0, 101*sizeof(float), stream);

  k_cvt<<<6400, 256, 0, stream>>>(x, xb);
  k_gemm<<<dim3(G_SPLIT,6), 256, 0, stream>>>(xb, aw, cw, partial ? P : Y, partial);
  if(partial){
    k_reduce<<<dim3((6*NN*CO+255)/256, 4), 256, 0, stream>>>(P, Y);
  }
  k_cheb<<<120, 128, 0, stream>>>(Y, ei, ab, cb, emb);
  k_fc<<<FCB+1, 256, 0, stream>>>(emb, afw, afb, cfw, cfb, s0, s1, s2, out);
}